// Round 13
// baseline (909.050 us; speedup 1.0000x reference)
//
#include <hip/hip_runtime.h>
#include <hip/hip_bf16.h>

typedef unsigned short u16;
typedef __bf16 bf16x8 __attribute__((ext_vector_type(8)));   // MFMA A/B operand (4 VGPRs)
typedef float  f32x4  __attribute__((ext_vector_type(4)));   // MFMA C/D operand
typedef u16    u16x8  __attribute__((ext_vector_type(8)));

#define HID   96
#define LDP   104          // padded LDS row stride for activation slices
#define MROWS 93312        // B*N*D
#define BN    10368        // B*N
#define GRID_TILE 1458     // MROWS/64

// B-fragment-ordered weights: 20 chunks x 18 frags x 512 elems (1KB frags)
// 0-2 cr (2=folded crW3@W1b), 3-5 dr (5=folded drW3@W1c), 6-7 unused,
// 8 gmW2_0, 9 gmW2_1, 10-11 rW12, 12-15 Wih (i,f,g,o), 16-19 Whh
#define FCH 9216           // elems per chunk (18*512)

#define MFMA(a,b,c) __builtin_amdgcn_mfma_f32_16x16x32_bf16((a),(b),(c),0,0,0)

__device__ __forceinline__ float bf2f(u16 x){
  union { float f; unsigned u; } v; v.u = ((unsigned)x) << 16; return v.f;
}
__device__ __forceinline__ u16 f2bf(float f){
  union { float f; unsigned u; } v; v.f = f;
  unsigned r = v.u + 0x7fffu + ((v.u >> 16) & 1u);   // RNE
  return (u16)(r >> 16);
}
__device__ __forceinline__ float bfr(float x){ return bf2f(f2bf(x)); }
__device__ __forceinline__ float sigf(float x){ return 1.f/(1.f + __expf(-x)); }
__device__ __forceinline__ float tanhf_(float x){
  float xx = fminf(fmaxf(x, -15.f), 15.f);
  float e = __expf(-2.f * xx);
  return (1.f - e) / (1.f + e);
}
__device__ __forceinline__ void lds_fence(){
  asm volatile("s_waitcnt lgkmcnt(0)" ::: "memory");
}

// ---- fragment loaders -------------------------------------------------------
struct Frags { bf16x8 a0, a1, a2; };

__device__ __forceinline__ Frags load_afrags_g(const u16* __restrict__ A, size_t row0, int lane){
  int t16 = lane & 15, q = lane >> 4;
  const u16* p = A + (row0 + (size_t)t16) * 96 + q * 8;
  Frags f;
  f.a0 = *reinterpret_cast<const bf16x8*>(p);
  f.a1 = *reinterpret_cast<const bf16x8*>(p + 32);
  f.a2 = *reinterpret_cast<const bf16x8*>(p + 64);
  return f;
}
__device__ __forceinline__ Frags load_afrags_s(const u16* sA, int row0, int lane){
  int t16 = lane & 15, q = lane >> 4;
  const u16* p = sA + (row0 + t16) * LDP + q * 8;
  Frags f;
  f.a0 = *reinterpret_cast<const bf16x8*>(p);
  f.a1 = *reinterpret_cast<const bf16x8*>(p + 32);
  f.a2 = *reinterpret_cast<const bf16x8*>(p + 64);
  return f;
}

// ---- one 16x96 layer, weights as global B-frags (L1/L2-resident) ------------
__device__ __forceinline__ void layer_g(Frags f, const u16* __restrict__ wb,
    const float* __restrict__ bias, u16* dst, int dstStride, size_t rowBase,
    bool relu, int lane)
{
  int t16 = lane & 15, q = lane >> 4;
  #pragma unroll
  for (int nt = 0; nt < 6; nt++){
    float b = bias ? bias[nt * 16 + t16] : 0.f;
    f32x4 acc = {b, b, b, b};
    const u16* wp = wb + nt * 1536 + lane * 8;
    acc = MFMA(f.a0, *reinterpret_cast<const bf16x8*>(wp),        acc);
    acc = MFMA(f.a1, *reinterpret_cast<const bf16x8*>(wp + 512),  acc);
    acc = MFMA(f.a2, *reinterpret_cast<const bf16x8*>(wp + 1024), acc);
    #pragma unroll
    for (int j = 0; j < 4; j++){
      float v = acc[j];
      if (relu) v = fmaxf(v, 0.f);
      dst[(rowBase + q * 4 + j) * (size_t)dstStride + nt * 16 + t16] = f2bf(v);
    }
  }
}

__device__ __forceinline__ void mfma6_g(f32x4* acc, int tbase, Frags f,
    const u16* __restrict__ wb, int lane)
{
  #pragma unroll
  for (int jt = 0; jt < 6; jt++){
    const u16* wp = wb + jt * 1536 + lane * 8;
    acc[tbase + jt] = MFMA(f.a0, *reinterpret_cast<const bf16x8*>(wp),        acc[tbase + jt]);
    acc[tbase + jt] = MFMA(f.a1, *reinterpret_cast<const bf16x8*>(wp + 512),  acc[tbase + jt]);
    acc[tbase + jt] = MFMA(f.a2, *reinterpret_cast<const bf16x8*>(wp + 1024), acc[tbase + jt]);
  }
}

// ============================================================================
// K_fold: f32 algebraic folds, cr/dr side only.
__global__ __launch_bounds__(256) void k_fold(const float* __restrict__ crW,
    const float* __restrict__ crB, const float* __restrict__ drW,
    const float* __restrict__ drB, const float* __restrict__ gmW1,
    float* __restrict__ Wf_cr, float* __restrict__ b_cr,
    float* __restrict__ Wf_dr, float* __restrict__ b_dr)
{
  int b = blockIdx.x, tid = threadIdx.x;
  const float* A  = (b == 0) ? crW + 18432 : drW + 18432;   // [k][n]
  const float* Bb = (b == 0) ? crB + 192   : drB + 192;
  const float* W1 = gmW1 + (b == 0 ? 9216 : 18432);         // [n][c]
  float* Wo = (b == 0) ? Wf_cr : Wf_dr;
  float* bo = (b == 0) ? b_cr  : b_dr;
  for (int i = tid; i < 9216; i += 256){
    int k = i / 96, c = i - k * 96;
    float s = 0.f;
    for (int n = 0; n < 96; n++) s += A[k * 96 + n] * W1[n * 96 + c];
    Wo[i] = s;
  }
  if (tid < 96){
    float s = 0.f;
    for (int n = 0; n < 96; n++) s += Bb[n] * W1[n * 96 + tid];
    bo[tid] = s;
  }
}

// K_tables2: XTab/XgTab + iter-0 Y/Z tables (bf16-faithful 3-layer chains).
__global__ void k_tables2(const float* __restrict__ eW1, const float* __restrict__ eb1,
    const float* __restrict__ eW2, const float* __restrict__ eb2,
    const float* __restrict__ gmW1, const float* __restrict__ gmb1,
    const float* __restrict__ crW, const float* __restrict__ crB,
    const float* __restrict__ drW, const float* __restrict__ drB,
    const float* __restrict__ Wf_cr, const float* __restrict__ b_cr,
    const float* __restrict__ Wf_dr, const float* __restrict__ b_dr,
    float* __restrict__ XTab, float* __restrict__ XgTab,
    float* __restrict__ YTab, float* __restrict__ ZTab)
{
  __shared__ float sX[3][96];
  __shared__ float tb[96], ub[96];
  int j = threadIdx.x;
  if (j < 96){
    for (int ch = 0; ch < 3; ch++){
      float acc = eb2[j];
      for (int e = 0; e < 16; e++){
        float hv = fmaxf(eW1[ch * 16 + e] + eb1[e], 0.f);
        acc += hv * eW2[e * 96 + j];
      }
      sX[ch][j] = acc;
      XTab[ch * 96 + j] = acc;
    }
  }
  __syncthreads();
  if (j < 96){
    for (int ch = 0; ch < 3; ch++){
      float acc = gmb1[j];
      for (int k = 0; k < 96; k++) acc += sX[ch][k] * gmW1[k * 96 + j];
      XgTab[ch * 96 + j] = acc;
    }
  }
  for (int net = 0; net < 2; net++){
    const float* W  = net ? drW  : crW;
    const float* Bs = net ? drB  : crB;
    const float* Wf = net ? Wf_dr : Wf_cr;
    const float* bf = net ? b_dr  : b_cr;
    float* outT = net ? ZTab : YTab;
    for (int ch = 0; ch < 3; ch++){
      if (j < 96) tb[j] = bfr(sX[ch][j]);
      __syncthreads();
      if (j < 96){
        float a = Bs[j];
        for (int k = 0; k < 96; k++) a += tb[k] * bfr(W[k * 96 + j]);
        ub[j] = bfr(fmaxf(a, 0.f));
      }
      __syncthreads();
      if (j < 96){
        float a = Bs[96 + j];
        for (int k = 0; k < 96; k++) a += ub[k] * bfr(W[9216 + k * 96 + j]);
        tb[j] = bfr(fmaxf(a, 0.f));
      }
      __syncthreads();
      if (j < 96){
        float a = bf[j];
        for (int k = 0; k < 96; k++) a += tb[k] * bfr(Wf[k * 96 + j]);
        outT[ch * 96 + j] = bfr(a);
      }
      __syncthreads();
    }
  }
}

// K_prep2: f32 weights (incl. cr/dr folds) -> bf16 B-fragment layout.
__global__ __launch_bounds__(256) void k_prep2(const float* __restrict__ crW,
    const float* __restrict__ drW, const float* __restrict__ gmW1,
    const float* __restrict__ gmW2, const float* __restrict__ rW12,
    const float* __restrict__ Wih, const float* __restrict__ Whh,
    const float* __restrict__ Wf_cr, const float* __restrict__ Wf_dr,
    u16* __restrict__ pWB)
{
  int b = blockIdx.x, tid = threadIdx.x;
  u16* dst = pWB + b * FCH;
  if (b < 12){
    const float* src;                           // row-major [k][n]
    if (b < 2)       src = crW  + b * 9216;
    else if (b == 2) src = Wf_cr;
    else if (b < 5)  src = drW  + (b - 3) * 9216;
    else if (b == 5) src = Wf_dr;
    else if (b == 6) src = gmW1 + 9216;
    else if (b == 7) src = gmW1 + 18432;
    else if (b < 10) src = gmW2 + (b - 8) * 9216;
    else             src = rW12 + (b - 10) * 9216;
    #pragma unroll
    for (int i = 0; i < 36; i++){
      int idx = tid + i * 256;
      int f = idx >> 9, rem = idx & 511, l = rem >> 3, j = rem & 7;
      int nt = f / 3, kc = f - nt * 3;
      int n = nt * 16 + (l & 15);
      int k = ((l >> 4) << 3) + kc * 32 + j;
      dst[idx] = f2bf(src[k * 96 + n]);
    }
  } else {
    int bb = b - 12;                            // 0..3 Wih chunks, 4..7 Whh
    const float* src = (bb < 4 ? Wih : Whh) + (bb & 3) * 9216;  // [n][k]
    #pragma unroll
    for (int i = 0; i < 36; i++){
      int idx = tid + i * 256;
      int f = idx >> 9, rem = idx & 511, l = rem >> 3, j = rem & 7;
      int nt = f / 3, kc = f - nt * 3;
      int n = nt * 16 + (l & 15);
      int k = ((l >> 4) << 3) + kc * 32 + j;
      dst[idx] = f2bf(src[n * 96 + k]);
    }
  }
}

// K_init2: h0, Y0, Z0 from tables
__global__ __launch_bounds__(256) void k_init2(const int* __restrict__ inputs,
    const float* __restrict__ XTab, const float* __restrict__ YTab,
    const float* __restrict__ ZTab, u16* __restrict__ h,
    u16* __restrict__ Y, u16* __restrict__ Z)
{
  int idx = blockIdx.x * 256 + threadIdx.x;     // exactly MROWS*12
  int m = idx / 12, h8 = idx - m * 12;
  int bn = m / 9, d = m - bn * 9;
  int inp = inputs[bn];
  int ch = (inp == 0) ? 0 : ((inp == d + 1) ? 1 : 2);
  const float* xt = XTab + ch * 96 + h8 * 8;
  const float* yt = YTab + ch * 96 + h8 * 8;
  const float* zt = ZTab + ch * 96 + h8 * 8;
  size_t off = (size_t)m * 96 + h8 * 8;
  u16x8 hv, yv, zv;
  #pragma unroll
  for (int e = 0; e < 8; e++){ hv[e] = f2bf(xt[e]); yv[e] = f2bf(yt[e]); zv[e] = f2bf(zt[e]); }
  *reinterpret_cast<u16x8*>(h + off) = hv;
  *reinterpret_cast<u16x8*>(Y + off) = yv;
  *reinterpret_cast<u16x8*>(Z + off) = zv;
}

__device__ __forceinline__ void addrow(float* s, const u16* p){
  u16x8 t = *reinterpret_cast<const u16x8*>(p);
  #pragma unroll
  for (int e = 0; e < 8; e++) s[e] += bf2f(t[e]);
}

// K_MSG: fused msgdigit (blocks 0..1151, Z in-place) + scell (1152.., Y->Ssum)
__global__ __launch_bounds__(256) void k_msg(u16* __restrict__ Z,
    const u16* __restrict__ Y, u16* __restrict__ Ssum)
{
  __shared__ u16 sT[81 * LDP];
  const int tid = threadIdx.x;
  if (blockIdx.x >= 1152){
    int idx = (blockIdx.x - 1152) * 256 + tid;  // exactly BN*12
    int bn = idx / 12, h8 = idx - bn * 12;
    const u16* base = Y + (size_t)bn * 864 + h8 * 8;
    float s[8];
    #pragma unroll
    for (int e = 0; e < 8; e++) s[e] = 0.f;
    #pragma unroll
    for (int d = 0; d < 9; d++){
      u16x8 v = *reinterpret_cast<const u16x8*>(base + d * 96);
      #pragma unroll
      for (int e = 0; e < 8; e++) s[e] += bf2f(v[e]);
    }
    u16x8 o;
    #pragma unroll
    for (int e = 0; e < 8; e++) o[e] = f2bf(s[e]);
    *reinterpret_cast<u16x8*>(Ssum + (size_t)bn * 96 + h8 * 8) = o;
    return;
  }
  const int b = blockIdx.x / 9, d = blockIdx.x - b * 9;
  const size_t base = ((size_t)b * 729 + d) * 96;
  for (int i = tid; i < 972; i += 256){
    int n = i / 12, k8 = i - n * 12;
    *reinterpret_cast<u16x8*>(sT + n * LDP + k8 * 8) =
      *reinterpret_cast<const u16x8*>(Z + base + (size_t)n * 864 + k8 * 8);
  }
  __syncthreads();
  for (int i = tid; i < 972; i += 256){
    int m = i / 12, k8 = i - m * 12;
    int r = m / 9, cc = m - r * 9;
    int br = (r / 3) * 3, bc = (cc / 3) * 3;
    float s[8];
    #pragma unroll
    for (int e = 0; e < 8; e++) s[e] = 0.f;
    #pragma unroll
    for (int c2 = 0; c2 < 9; c2++) if (c2 != cc) addrow(s, sT + (r * 9 + c2) * LDP + k8 * 8);
    #pragma unroll
    for (int r2 = 0; r2 < 9; r2++) if (r2 != r) addrow(s, sT + (r2 * 9 + cc) * LDP + k8 * 8);
    #pragma unroll
    for (int r2 = 0; r2 < 3; r2++)
      #pragma unroll
      for (int c2 = 0; c2 < 3; c2++){
        int rr = br + r2, c3 = bc + c2;
        if (rr != r && c3 != cc) addrow(s, sT + (rr * 9 + c3) * LDP + k8 * 8);
      }
    u16x8 o;
    #pragma unroll
    for (int e = 0; e < 8; e++) o[e] = f2bf(s[e]);
    *reinterpret_cast<u16x8*>(Z + base + (size_t)m * 864 + k8 * 8) = o;
  }
}

// K_GLR9: glr8 main body (unchanged register peak) + fused ab tail producing
// next-iter Y/Z from h (in sA). notLast gates cout/h writes + Y/Z production.
__global__ __launch_bounds__(256) void k_glr9(const u16* __restrict__ Yin,
    const u16* __restrict__ Zd, const u16* __restrict__ Ssum,
    const int* __restrict__ inputs, const float* __restrict__ XgTab,
    const u16* __restrict__ pWB, const float* __restrict__ gmb2,
    u16* __restrict__ h, const float* __restrict__ cin, float* __restrict__ cout,
    const float* __restrict__ bih, const float* __restrict__ bhh,
    const float* __restrict__ crB, const float* __restrict__ drB,
    const float* __restrict__ b_cr, const float* __restrict__ b_dr,
    u16* __restrict__ Yout, u16* __restrict__ Zout,
    const float* __restrict__ rb12, const float* __restrict__ rW3,
    const float* __restrict__ rb3, float* __restrict__ out, int notLast)
{
  __shared__ u16 sA[64 * LDP];
  const int tid = threadIdx.x, lane = tid & 63, wave = tid >> 6;
  const int t16 = lane & 15, q = lane >> 4;
  const int wrow = wave * 16;
  const size_t rbase = (size_t)blockIdx.x * 64;

  // EARLY: issue all HBM reads this wave will ever need
  float cold[6][4];
  #pragma unroll
  for (int jt = 0; jt < 6; jt++)
    #pragma unroll
    for (int j = 0; j < 4; j++)
      cold[jt][j] = cin[(rbase + wrow + q * 4 + j) * 96 + jt * 16 + t16];
  Frags ah = load_afrags_g(h, rbase + wrow, lane);

  // g1 = relu(Xg[ch] + (Ssum - Y) + Zd) -> own sA rows
  for (int i = lane; i < 192; i += 64){
    int rl = i / 12, kc = i - rl * 12;
    int m = (int)rbase + wrow + rl;
    int bn = m / 9, d = m - bn * 9;
    int inp = inputs[bn];
    int ch = (inp == 0) ? 0 : ((inp == d + 1) ? 1 : 2);
    const float* xg = XgTab + ch * 96 + kc * 8;
    u16x8 vy = *reinterpret_cast<const u16x8*>(Yin  + (size_t)m * 96 + kc * 8);
    u16x8 vz = *reinterpret_cast<const u16x8*>(Zd   + (size_t)m * 96 + kc * 8);
    u16x8 vs = *reinterpret_cast<const u16x8*>(Ssum + (size_t)bn * 96 + kc * 8);
    u16x8 o;
    #pragma unroll
    for (int e = 0; e < 8; e++)
      o[e] = f2bf(fmaxf(xg[e] + bf2f(vs[e]) - bf2f(vy[e]) + bf2f(vz[e]), 0.f));
    *reinterpret_cast<u16x8*>(sA + (wrow + rl) * LDP + kc * 8) = o;
  }
  lds_fence();

  Frags f = load_afrags_s(sA, wrow, lane);
  layer_g(f, pWB + 8 * FCH, gmb2, sA, LDP, wrow, true, lane);        lds_fence();
  f = load_afrags_s(sA, wrow, lane);
  layer_g(f, pWB + 9 * FCH, gmb2 + 96, sA, LDP, wrow, false, lane);  lds_fence();
  Frags ax = load_afrags_s(sA, wrow, lane);

  // LSTM gates: 24 col-tiles (n = 0..383)
  f32x4 acc[24];
  #pragma unroll
  for (int t = 0; t < 24; t++){
    int n = t * 16 + t16;
    float b = bih[n] + bhh[n];
    f32x4 a = {b, b, b, b};
    acc[t] = a;
  }
  #pragma unroll
  for (int c = 0; c < 4; c++) mfma6_g(acc, c * 6, ax, pWB + (12 + c) * FCH, lane);
  #pragma unroll
  for (int c = 0; c < 4; c++) mfma6_g(acc, c * 6, ah, pWB + (16 + c) * FCH, lane);

  // Epilogue: c/h update; h_new -> sA (always) + global (if not last)
  #pragma unroll
  for (int jt = 0; jt < 6; jt++)
    #pragma unroll
    for (int j = 0; j < 4; j++){
      size_t m = rbase + wrow + q * 4 + j;
      int col = jt * 16 + t16;
      float iv = acc[0 * 6 + jt][j];
      float fv = acc[1 * 6 + jt][j];
      float gv = acc[2 * 6 + jt][j];
      float ov = acc[3 * 6 + jt][j];
      float cn = sigf(fv) * cold[jt][j] + sigf(iv) * tanhf_(gv);
      float hn = sigf(ov) * tanhf_(cn);
      u16 hb = f2bf(hn);
      if (notLast){
        cout[m * 96 + col] = cn;
        h[m * 96 + col] = hb;
      }
      sA[(wrow + q * 4 + j) * LDP + col] = hb;
    }
  lds_fence();

  // h fragments held in registers across the tail (sA gets reused as scratch)
  Frags hf = load_afrags_s(sA, wrow, lane);

  if (notLast){
    // ---- fused ab tail: Y = fold(cr3(h)), Z = fold(dr3(h)) for next iter ----
    layer_g(hf, pWB, crB, sA, LDP, wrow, true, lane);                  lds_fence();
    Frags t = load_afrags_s(sA, wrow, lane);
    layer_g(t, pWB + 1 * FCH, crB + 96, sA, LDP, wrow, true, lane);    lds_fence();
    t = load_afrags_s(sA, wrow, lane);
    layer_g(t, pWB + 2 * FCH, b_cr, Yout, 96, rbase + wrow, false, lane);
    lds_fence();
    layer_g(hf, pWB + 3 * FCH, drB, sA, LDP, wrow, true, lane);        lds_fence();
    t = load_afrags_s(sA, wrow, lane);
    layer_g(t, pWB + 4 * FCH, drB + 96, sA, LDP, wrow, true, lane);    lds_fence();
    t = load_afrags_s(sA, wrow, lane);
    layer_g(t, pWB + 5 * FCH, b_dr, Zout, 96, rbase + wrow, false, lane);
    lds_fence();
  }

  // Readout (input = hf, bit-identical to reading h from sA)
  layer_g(hf, pWB + 10 * FCH, rb12, sA, LDP, wrow, true, lane);        lds_fence();
  Frags t2 = load_afrags_s(sA, wrow, lane);
  layer_g(t2, pWB + 11 * FCH, rb12 + 96, sA, LDP, wrow, true, lane);   lds_fence();

  int row = tid >> 2, part = tid & 3;
  float s = 0.f;
  const u16* rp = sA + row * LDP + part * 24;
  #pragma unroll
  for (int k = 0; k < 24; k++) s += bf2f(rp[k]) * rW3[part * 24 + k];
  s += __shfl_xor(s, 1);
  s += __shfl_xor(s, 2);
  if (part == 0) out[rbase + row] = s + rb3[0];
}

// ============================================================================
extern "C" void kernel_launch(void* const* d_in, const int* in_sizes, int n_in,
                              void* d_out, int out_size, void* d_ws, size_t ws_size,
                              hipStream_t stream)
{
  (void)in_sizes; (void)n_in; (void)out_size; (void)ws_size;
  const int*   inputs = (const int*)d_in[0];
  const float* c0     = (const float*)d_in[1];
  const float* eW1  = (const float*)d_in[4];
  const float* eb1  = (const float*)d_in[5];
  const float* eW2  = (const float*)d_in[6];
  const float* eb2  = (const float*)d_in[7];
  const float* crW  = (const float*)d_in[8];
  const float* crB  = (const float*)d_in[9];
  const float* drW  = (const float*)d_in[10];
  const float* drB  = (const float*)d_in[11];
  const float* gmW1 = (const float*)d_in[12];
  const float* gmb1 = (const float*)d_in[13];
  const float* gmW2 = (const float*)d_in[14];
  const float* gmb2 = (const float*)d_in[15];
  const float* Wih  = (const float*)d_in[16];
  const float* Whh  = (const float*)d_in[17];
  const float* bih  = (const float*)d_in[18];
  const float* bhh  = (const float*)d_in[19];
  const float* rW12 = (const float*)d_in[20];
  const float* rb12 = (const float*)d_in[21];
  const float* rW3  = (const float*)d_in[22];
  const float* rb3  = (const float*)d_in[23];

  char* ws = (char*)d_ws;
  float* XgTab = (float*)(ws);
  float* XTab  = (float*)(ws + 2048);
  float* YTab  = (float*)(ws + 4096);
  float* ZTab  = (float*)(ws + 6144);
  float* Wf_cr = (float*)(ws + 8192);            // 9216 f
  float* b_cr  = (float*)(ws + 45056);           // 96 f
  float* Wf_dr = (float*)(ws + 45568);           // 9216 f
  float* b_dr  = (float*)(ws + 82432);           // 96 f
  u16*   pWB   = (u16*)(ws + 233472);            // 368640 B
  u16* h  = (u16*)(ws + 634880);
  u16* B1 = h  + (size_t)MROWS * 96;             // Y
  u16* B2 = B1 + (size_t)MROWS * 96;             // Z / Zd
  float* c = (float*)(B2 + (size_t)MROWS * 96);
  u16* Ssum = (u16*)(c + (size_t)MROWS * 96);    // BN*96 bf16
  float* out = (float*)d_out;

  k_fold<<<2, 256, 0, stream>>>(crW, crB, drW, drB, gmW1,
                                Wf_cr, b_cr, Wf_dr, b_dr);
  k_tables2<<<1, 128, 0, stream>>>(eW1, eb1, eW2, eb2, gmW1, gmb1,
                                   crW, crB, drW, drB, Wf_cr, b_cr, Wf_dr, b_dr,
                                   XTab, XgTab, YTab, ZTab);
  k_prep2<<<20, 256, 0, stream>>>(crW, drW, gmW1, gmW2, rW12, Wih, Whh,
                                  Wf_cr, Wf_dr, pWB);
  k_init2<<<(MROWS * 12) / 256, 256, 0, stream>>>(inputs, XTab, YTab, ZTab, h, B1, B2);

  for (int it = 0; it < 4; ++it){
    const float* cin = (it == 0) ? c0 : c;
    k_msg<<<1152 + 486, 256, 0, stream>>>(B2, B1, Ssum);
    k_glr9<<<GRID_TILE, 256, 0, stream>>>(B1, B2, Ssum, inputs, XgTab, pWB, gmb2,
                                          h, cin, c, bih, bhh, crB, drB, b_cr, b_dr,
                                          B1, B2, rb12, rW3, rb3,
                                          out + (size_t)it * MROWS, (it < 3) ? 1 : 0);
  }
}

// Round 14
// 888.354 us; speedup vs baseline: 1.0233x; 1.0233x over previous
//
#include <hip/hip_runtime.h>
#include <hip/hip_bf16.h>

typedef unsigned short u16;
typedef __bf16 bf16x8 __attribute__((ext_vector_type(8)));   // MFMA A/B operand (4 VGPRs)
typedef float  f32x4  __attribute__((ext_vector_type(4)));   // MFMA C/D operand
typedef u16    u16x8  __attribute__((ext_vector_type(8)));

#define HID   96
#define LDP   104          // padded LDS row stride for activation slices
#define MROWS 93312        // B*N*D
#define BN    10368        // B*N
#define GRID_TILE 1458     // MROWS/64

// B-fragment-ordered weights: 20 chunks x 18 frags x 512 elems (1KB frags)
// 0-2 cr (2=folded crW3@W1b), 3-5 dr (5=folded drW3@W1c), 6-7 unused,
// 8 gmW2_0, 9 gmW2_1, 10-11 rW12, 12-15 Wih (i,f,g,o), 16-19 Whh
#define FCH 9216           // elems per chunk (18*512)

#define MFMA(a,b,c) __builtin_amdgcn_mfma_f32_16x16x32_bf16((a),(b),(c),0,0,0)

__device__ __forceinline__ float bf2f(u16 x){
  union { float f; unsigned u; } v; v.u = ((unsigned)x) << 16; return v.f;
}
__device__ __forceinline__ u16 f2bf(float f){
  union { float f; unsigned u; } v; v.f = f;
  unsigned r = v.u + 0x7fffu + ((v.u >> 16) & 1u);   // RNE
  return (u16)(r >> 16);
}
__device__ __forceinline__ float bfr(float x){ return bf2f(f2bf(x)); }
// fp16 c-state converters (RNE both ways; ~0.05% rel error, 8x tighter than bf16)
__device__ __forceinline__ float h2f(u16 x){
  union { u16 u; _Float16 h; } v; v.u = x; return (float)v.h;
}
__device__ __forceinline__ u16 f2h(float f){
  union { u16 u; _Float16 h; } v; v.h = (_Float16)f; return v.u;
}
__device__ __forceinline__ float sigf(float x){ return 1.f/(1.f + __expf(-x)); }
__device__ __forceinline__ float tanhf_(float x){
  float xx = fminf(fmaxf(x, -15.f), 15.f);
  float e = __expf(-2.f * xx);
  return (1.f - e) / (1.f + e);
}
__device__ __forceinline__ void lds_fence(){
  asm volatile("s_waitcnt lgkmcnt(0)" ::: "memory");
}

// ---- fragment loaders -------------------------------------------------------
struct Frags { bf16x8 a0, a1, a2; };

__device__ __forceinline__ Frags load_afrags_g(const u16* __restrict__ A, size_t row0, int lane){
  int t16 = lane & 15, q = lane >> 4;
  const u16* p = A + (row0 + (size_t)t16) * 96 + q * 8;
  Frags f;
  f.a0 = *reinterpret_cast<const bf16x8*>(p);
  f.a1 = *reinterpret_cast<const bf16x8*>(p + 32);
  f.a2 = *reinterpret_cast<const bf16x8*>(p + 64);
  return f;
}
__device__ __forceinline__ Frags load_afrags_s(const u16* sA, int row0, int lane){
  int t16 = lane & 15, q = lane >> 4;
  const u16* p = sA + (row0 + t16) * LDP + q * 8;
  Frags f;
  f.a0 = *reinterpret_cast<const bf16x8*>(p);
  f.a1 = *reinterpret_cast<const bf16x8*>(p + 32);
  f.a2 = *reinterpret_cast<const bf16x8*>(p + 64);
  return f;
}

// ---- one 16x96 layer, weights as global B-frags (L1/L2-resident) ------------
__device__ __forceinline__ void layer_g(Frags f, const u16* __restrict__ wb,
    const float* __restrict__ bias, u16* dst, int dstStride, size_t rowBase,
    bool relu, int lane)
{
  int t16 = lane & 15, q = lane >> 4;
  #pragma unroll
  for (int nt = 0; nt < 6; nt++){
    float b = bias ? bias[nt * 16 + t16] : 0.f;
    f32x4 acc = {b, b, b, b};
    const u16* wp = wb + nt * 1536 + lane * 8;
    acc = MFMA(f.a0, *reinterpret_cast<const bf16x8*>(wp),        acc);
    acc = MFMA(f.a1, *reinterpret_cast<const bf16x8*>(wp + 512),  acc);
    acc = MFMA(f.a2, *reinterpret_cast<const bf16x8*>(wp + 1024), acc);
    #pragma unroll
    for (int j = 0; j < 4; j++){
      float v = acc[j];
      if (relu) v = fmaxf(v, 0.f);
      dst[(rowBase + q * 4 + j) * (size_t)dstStride + nt * 16 + t16] = f2bf(v);
    }
  }
}

__device__ __forceinline__ void mfma6_g(f32x4* acc, int tbase, Frags f,
    const u16* __restrict__ wb, int lane)
{
  #pragma unroll
  for (int jt = 0; jt < 6; jt++){
    const u16* wp = wb + jt * 1536 + lane * 8;
    acc[tbase + jt] = MFMA(f.a0, *reinterpret_cast<const bf16x8*>(wp),        acc[tbase + jt]);
    acc[tbase + jt] = MFMA(f.a1, *reinterpret_cast<const bf16x8*>(wp + 512),  acc[tbase + jt]);
    acc[tbase + jt] = MFMA(f.a2, *reinterpret_cast<const bf16x8*>(wp + 1024), acc[tbase + jt]);
  }
}

// ============================================================================
// K_fold: f32 algebraic folds, cr/dr side only.
__global__ __launch_bounds__(256) void k_fold(const float* __restrict__ crW,
    const float* __restrict__ crB, const float* __restrict__ drW,
    const float* __restrict__ drB, const float* __restrict__ gmW1,
    float* __restrict__ Wf_cr, float* __restrict__ b_cr,
    float* __restrict__ Wf_dr, float* __restrict__ b_dr)
{
  int b = blockIdx.x, tid = threadIdx.x;
  const float* A  = (b == 0) ? crW + 18432 : drW + 18432;   // [k][n]
  const float* Bb = (b == 0) ? crB + 192   : drB + 192;
  const float* W1 = gmW1 + (b == 0 ? 9216 : 18432);         // [n][c]
  float* Wo = (b == 0) ? Wf_cr : Wf_dr;
  float* bo = (b == 0) ? b_cr  : b_dr;
  for (int i = tid; i < 9216; i += 256){
    int k = i / 96, c = i - k * 96;
    float s = 0.f;
    for (int n = 0; n < 96; n++) s += A[k * 96 + n] * W1[n * 96 + c];
    Wo[i] = s;
  }
  if (tid < 96){
    float s = 0.f;
    for (int n = 0; n < 96; n++) s += Bb[n] * W1[n * 96 + tid];
    bo[tid] = s;
  }
}

// K_tables2: XTab/XgTab + iter-0 Y/Z tables (bf16-faithful 3-layer chains).
__global__ void k_tables2(const float* __restrict__ eW1, const float* __restrict__ eb1,
    const float* __restrict__ eW2, const float* __restrict__ eb2,
    const float* __restrict__ gmW1, const float* __restrict__ gmb1,
    const float* __restrict__ crW, const float* __restrict__ crB,
    const float* __restrict__ drW, const float* __restrict__ drB,
    const float* __restrict__ Wf_cr, const float* __restrict__ b_cr,
    const float* __restrict__ Wf_dr, const float* __restrict__ b_dr,
    float* __restrict__ XTab, float* __restrict__ XgTab,
    float* __restrict__ YTab, float* __restrict__ ZTab)
{
  __shared__ float sX[3][96];
  __shared__ float tb[96], ub[96];
  int j = threadIdx.x;
  if (j < 96){
    for (int ch = 0; ch < 3; ch++){
      float acc = eb2[j];
      for (int e = 0; e < 16; e++){
        float hv = fmaxf(eW1[ch * 16 + e] + eb1[e], 0.f);
        acc += hv * eW2[e * 96 + j];
      }
      sX[ch][j] = acc;
      XTab[ch * 96 + j] = acc;
    }
  }
  __syncthreads();
  if (j < 96){
    for (int ch = 0; ch < 3; ch++){
      float acc = gmb1[j];
      for (int k = 0; k < 96; k++) acc += sX[ch][k] * gmW1[k * 96 + j];
      XgTab[ch * 96 + j] = acc;
    }
  }
  for (int net = 0; net < 2; net++){
    const float* W  = net ? drW  : crW;
    const float* Bs = net ? drB  : crB;
    const float* Wf = net ? Wf_dr : Wf_cr;
    const float* bf = net ? b_dr  : b_cr;
    float* outT = net ? ZTab : YTab;
    for (int ch = 0; ch < 3; ch++){
      if (j < 96) tb[j] = bfr(sX[ch][j]);
      __syncthreads();
      if (j < 96){
        float a = Bs[j];
        for (int k = 0; k < 96; k++) a += tb[k] * bfr(W[k * 96 + j]);
        ub[j] = bfr(fmaxf(a, 0.f));
      }
      __syncthreads();
      if (j < 96){
        float a = Bs[96 + j];
        for (int k = 0; k < 96; k++) a += ub[k] * bfr(W[9216 + k * 96 + j]);
        tb[j] = bfr(fmaxf(a, 0.f));
      }
      __syncthreads();
      if (j < 96){
        float a = bf[j];
        for (int k = 0; k < 96; k++) a += tb[k] * bfr(Wf[k * 96 + j]);
        outT[ch * 96 + j] = bfr(a);
      }
      __syncthreads();
    }
  }
}

// K_prep2: f32 weights (incl. cr/dr folds) -> bf16 B-fragment layout.
__global__ __launch_bounds__(256) void k_prep2(const float* __restrict__ crW,
    const float* __restrict__ drW, const float* __restrict__ gmW1,
    const float* __restrict__ gmW2, const float* __restrict__ rW12,
    const float* __restrict__ Wih, const float* __restrict__ Whh,
    const float* __restrict__ Wf_cr, const float* __restrict__ Wf_dr,
    u16* __restrict__ pWB)
{
  int b = blockIdx.x, tid = threadIdx.x;
  u16* dst = pWB + b * FCH;
  if (b < 12){
    const float* src;                           // row-major [k][n]
    if (b < 2)       src = crW  + b * 9216;
    else if (b == 2) src = Wf_cr;
    else if (b < 5)  src = drW  + (b - 3) * 9216;
    else if (b == 5) src = Wf_dr;
    else if (b == 6) src = gmW1 + 9216;
    else if (b == 7) src = gmW1 + 18432;
    else if (b < 10) src = gmW2 + (b - 8) * 9216;
    else             src = rW12 + (b - 10) * 9216;
    #pragma unroll
    for (int i = 0; i < 36; i++){
      int idx = tid + i * 256;
      int f = idx >> 9, rem = idx & 511, l = rem >> 3, j = rem & 7;
      int nt = f / 3, kc = f - nt * 3;
      int n = nt * 16 + (l & 15);
      int k = ((l >> 4) << 3) + kc * 32 + j;
      dst[idx] = f2bf(src[k * 96 + n]);
    }
  } else {
    int bb = b - 12;                            // 0..3 Wih chunks, 4..7 Whh
    const float* src = (bb < 4 ? Wih : Whh) + (bb & 3) * 9216;  // [n][k]
    #pragma unroll
    for (int i = 0; i < 36; i++){
      int idx = tid + i * 256;
      int f = idx >> 9, rem = idx & 511, l = rem >> 3, j = rem & 7;
      int nt = f / 3, kc = f - nt * 3;
      int n = nt * 16 + (l & 15);
      int k = ((l >> 4) << 3) + kc * 32 + j;
      dst[idx] = f2bf(src[n * 96 + k]);
    }
  }
}

// K_init2: h0, Y0, Z0 from tables + c0 (f32) -> ch (fp16)
__global__ __launch_bounds__(256) void k_init2(const int* __restrict__ inputs,
    const float* __restrict__ XTab, const float* __restrict__ YTab,
    const float* __restrict__ ZTab, const float* __restrict__ c0,
    u16* __restrict__ h, u16* __restrict__ Y, u16* __restrict__ Z,
    u16* __restrict__ ch16)
{
  int idx = blockIdx.x * 256 + threadIdx.x;     // exactly MROWS*12
  int m = idx / 12, h8 = idx - m * 12;
  int bn = m / 9, d = m - bn * 9;
  int inp = inputs[bn];
  int ch = (inp == 0) ? 0 : ((inp == d + 1) ? 1 : 2);
  const float* xt = XTab + ch * 96 + h8 * 8;
  const float* yt = YTab + ch * 96 + h8 * 8;
  const float* zt = ZTab + ch * 96 + h8 * 8;
  size_t off = (size_t)m * 96 + h8 * 8;
  const float* cs = c0 + off;
  u16x8 hv, yv, zv, cv;
  #pragma unroll
  for (int e = 0; e < 8; e++){
    hv[e] = f2bf(xt[e]); yv[e] = f2bf(yt[e]); zv[e] = f2bf(zt[e]);
    cv[e] = f2h(cs[e]);
  }
  *reinterpret_cast<u16x8*>(h + off) = hv;
  *reinterpret_cast<u16x8*>(Y + off) = yv;
  *reinterpret_cast<u16x8*>(Z + off) = zv;
  *reinterpret_cast<u16x8*>(ch16 + off) = cv;
}

__device__ __forceinline__ void addrow(float* s, const u16* p){
  u16x8 t = *reinterpret_cast<const u16x8*>(p);
  #pragma unroll
  for (int e = 0; e < 8; e++) s[e] += bf2f(t[e]);
}

// K_MSG: fused msgdigit (blocks 0..1151, Z in-place) + scell (1152.., Y->Ssum)
__global__ __launch_bounds__(256) void k_msg(u16* __restrict__ Z,
    const u16* __restrict__ Y, u16* __restrict__ Ssum)
{
  __shared__ u16 sT[81 * LDP];
  const int tid = threadIdx.x;
  if (blockIdx.x >= 1152){
    int idx = (blockIdx.x - 1152) * 256 + tid;  // exactly BN*12
    int bn = idx / 12, h8 = idx - bn * 12;
    const u16* base = Y + (size_t)bn * 864 + h8 * 8;
    float s[8];
    #pragma unroll
    for (int e = 0; e < 8; e++) s[e] = 0.f;
    #pragma unroll
    for (int d = 0; d < 9; d++){
      u16x8 v = *reinterpret_cast<const u16x8*>(base + d * 96);
      #pragma unroll
      for (int e = 0; e < 8; e++) s[e] += bf2f(v[e]);
    }
    u16x8 o;
    #pragma unroll
    for (int e = 0; e < 8; e++) o[e] = f2bf(s[e]);
    *reinterpret_cast<u16x8*>(Ssum + (size_t)bn * 96 + h8 * 8) = o;
    return;
  }
  const int b = blockIdx.x / 9, d = blockIdx.x - b * 9;
  const size_t base = ((size_t)b * 729 + d) * 96;
  for (int i = tid; i < 972; i += 256){
    int n = i / 12, k8 = i - n * 12;
    *reinterpret_cast<u16x8*>(sT + n * LDP + k8 * 8) =
      *reinterpret_cast<const u16x8*>(Z + base + (size_t)n * 864 + k8 * 8);
  }
  __syncthreads();
  for (int i = tid; i < 972; i += 256){
    int m = i / 12, k8 = i - m * 12;
    int r = m / 9, cc = m - r * 9;
    int br = (r / 3) * 3, bc = (cc / 3) * 3;
    float s[8];
    #pragma unroll
    for (int e = 0; e < 8; e++) s[e] = 0.f;
    #pragma unroll
    for (int c2 = 0; c2 < 9; c2++) if (c2 != cc) addrow(s, sT + (r * 9 + c2) * LDP + k8 * 8);
    #pragma unroll
    for (int r2 = 0; r2 < 9; r2++) if (r2 != r) addrow(s, sT + (r2 * 9 + cc) * LDP + k8 * 8);
    #pragma unroll
    for (int r2 = 0; r2 < 3; r2++)
      #pragma unroll
      for (int c2 = 0; c2 < 3; c2++){
        int rr = br + r2, c3 = bc + c2;
        if (rr != r && c3 != cc) addrow(s, sT + (rr * 9 + c3) * LDP + k8 * 8);
      }
    u16x8 o;
    #pragma unroll
    for (int e = 0; e < 8; e++) o[e] = f2bf(s[e]);
    *reinterpret_cast<u16x8*>(Z + base + (size_t)m * 864 + k8 * 8) = o;
  }
}

// K_GLR10: glr9 structure with fp16 c-state (halves the dominant HBM stream).
// In-place c (cin==cout) is safe: each block reads its rows at entry only.
__global__ __launch_bounds__(256) void k_glr10(const u16* __restrict__ Yin,
    const u16* __restrict__ Zd, const u16* __restrict__ Ssum,
    const int* __restrict__ inputs, const float* __restrict__ XgTab,
    const u16* __restrict__ pWB, const float* __restrict__ gmb2,
    u16* __restrict__ h, u16* __restrict__ cbuf,
    const float* __restrict__ bih, const float* __restrict__ bhh,
    const float* __restrict__ crB, const float* __restrict__ drB,
    const float* __restrict__ b_cr, const float* __restrict__ b_dr,
    u16* __restrict__ Yout, u16* __restrict__ Zout,
    const float* __restrict__ rb12, const float* __restrict__ rW3,
    const float* __restrict__ rb3, float* __restrict__ out, int notLast)
{
  __shared__ u16 sA[64 * LDP];
  const int tid = threadIdx.x, lane = tid & 63, wave = tid >> 6;
  const int t16 = lane & 15, q = lane >> 4;
  const int wrow = wave * 16;
  const size_t rbase = (size_t)blockIdx.x * 64;

  // EARLY: issue all HBM reads this wave will ever need
  float cold[6][4];
  #pragma unroll
  for (int jt = 0; jt < 6; jt++)
    #pragma unroll
    for (int j = 0; j < 4; j++)
      cold[jt][j] = h2f(cbuf[(rbase + wrow + q * 4 + j) * 96 + jt * 16 + t16]);
  Frags ah = load_afrags_g(h, rbase + wrow, lane);

  // g1 = relu(Xg[ch] + (Ssum - Y) + Zd) -> own sA rows
  for (int i = lane; i < 192; i += 64){
    int rl = i / 12, kc = i - rl * 12;
    int m = (int)rbase + wrow + rl;
    int bn = m / 9, d = m - bn * 9;
    int inp = inputs[bn];
    int ch = (inp == 0) ? 0 : ((inp == d + 1) ? 1 : 2);
    const float* xg = XgTab + ch * 96 + kc * 8;
    u16x8 vy = *reinterpret_cast<const u16x8*>(Yin  + (size_t)m * 96 + kc * 8);
    u16x8 vz = *reinterpret_cast<const u16x8*>(Zd   + (size_t)m * 96 + kc * 8);
    u16x8 vs = *reinterpret_cast<const u16x8*>(Ssum + (size_t)bn * 96 + kc * 8);
    u16x8 o;
    #pragma unroll
    for (int e = 0; e < 8; e++)
      o[e] = f2bf(fmaxf(xg[e] + bf2f(vs[e]) - bf2f(vy[e]) + bf2f(vz[e]), 0.f));
    *reinterpret_cast<u16x8*>(sA + (wrow + rl) * LDP + kc * 8) = o;
  }
  lds_fence();

  Frags f = load_afrags_s(sA, wrow, lane);
  layer_g(f, pWB + 8 * FCH, gmb2, sA, LDP, wrow, true, lane);        lds_fence();
  f = load_afrags_s(sA, wrow, lane);
  layer_g(f, pWB + 9 * FCH, gmb2 + 96, sA, LDP, wrow, false, lane);  lds_fence();
  Frags ax = load_afrags_s(sA, wrow, lane);

  // LSTM gates: 24 col-tiles (n = 0..383)
  f32x4 acc[24];
  #pragma unroll
  for (int t = 0; t < 24; t++){
    int n = t * 16 + t16;
    float b = bih[n] + bhh[n];
    f32x4 a = {b, b, b, b};
    acc[t] = a;
  }
  #pragma unroll
  for (int c = 0; c < 4; c++) mfma6_g(acc, c * 6, ax, pWB + (12 + c) * FCH, lane);
  #pragma unroll
  for (int c = 0; c < 4; c++) mfma6_g(acc, c * 6, ah, pWB + (16 + c) * FCH, lane);

  // Epilogue: c/h update; h_new -> sA (always) + global (if not last)
  #pragma unroll
  for (int jt = 0; jt < 6; jt++)
    #pragma unroll
    for (int j = 0; j < 4; j++){
      size_t m = rbase + wrow + q * 4 + j;
      int col = jt * 16 + t16;
      float iv = acc[0 * 6 + jt][j];
      float fv = acc[1 * 6 + jt][j];
      float gv = acc[2 * 6 + jt][j];
      float ov = acc[3 * 6 + jt][j];
      float cn = sigf(fv) * cold[jt][j] + sigf(iv) * tanhf_(gv);
      float hn = sigf(ov) * tanhf_(cn);
      u16 hb = f2bf(hn);
      if (notLast){
        cbuf[m * 96 + col] = f2h(cn);
        h[m * 96 + col] = hb;
      }
      sA[(wrow + q * 4 + j) * LDP + col] = hb;
    }
  lds_fence();

  // h fragments held in registers across the tail
  Frags hf = load_afrags_s(sA, wrow, lane);

  if (notLast){
    // ---- fused ab tail: Y = fold(cr3(h)), Z = fold(dr3(h)) for next iter ----
    layer_g(hf, pWB, crB, sA, LDP, wrow, true, lane);                  lds_fence();
    Frags t = load_afrags_s(sA, wrow, lane);
    layer_g(t, pWB + 1 * FCH, crB + 96, sA, LDP, wrow, true, lane);    lds_fence();
    t = load_afrags_s(sA, wrow, lane);
    layer_g(t, pWB + 2 * FCH, b_cr, Yout, 96, rbase + wrow, false, lane);
    lds_fence();
    layer_g(hf, pWB + 3 * FCH, drB, sA, LDP, wrow, true, lane);        lds_fence();
    t = load_afrags_s(sA, wrow, lane);
    layer_g(t, pWB + 4 * FCH, drB + 96, sA, LDP, wrow, true, lane);    lds_fence();
    t = load_afrags_s(sA, wrow, lane);
    layer_g(t, pWB + 5 * FCH, b_dr, Zout, 96, rbase + wrow, false, lane);
    lds_fence();
  }

  // Readout
  layer_g(hf, pWB + 10 * FCH, rb12, sA, LDP, wrow, true, lane);        lds_fence();
  Frags t2 = load_afrags_s(sA, wrow, lane);
  layer_g(t2, pWB + 11 * FCH, rb12 + 96, sA, LDP, wrow, true, lane);   lds_fence();

  int row = tid >> 2, part = tid & 3;
  float s = 0.f;
  const u16* rp = sA + row * LDP + part * 24;
  #pragma unroll
  for (int k = 0; k < 24; k++) s += bf2f(rp[k]) * rW3[part * 24 + k];
  s += __shfl_xor(s, 1);
  s += __shfl_xor(s, 2);
  if (part == 0) out[rbase + row] = s + rb3[0];
}

// ============================================================================
extern "C" void kernel_launch(void* const* d_in, const int* in_sizes, int n_in,
                              void* d_out, int out_size, void* d_ws, size_t ws_size,
                              hipStream_t stream)
{
  (void)in_sizes; (void)n_in; (void)out_size; (void)ws_size;
  const int*   inputs = (const int*)d_in[0];
  const float* c0     = (const float*)d_in[1];
  const float* eW1  = (const float*)d_in[4];
  const float* eb1  = (const float*)d_in[5];
  const float* eW2  = (const float*)d_in[6];
  const float* eb2  = (const float*)d_in[7];
  const float* crW  = (const float*)d_in[8];
  const float* crB  = (const float*)d_in[9];
  const float* drW  = (const float*)d_in[10];
  const float* drB  = (const float*)d_in[11];
  const float* gmW1 = (const float*)d_in[12];
  const float* gmb1 = (const float*)d_in[13];
  const float* gmW2 = (const float*)d_in[14];
  const float* gmb2 = (const float*)d_in[15];
  const float* Wih  = (const float*)d_in[16];
  const float* Whh  = (const float*)d_in[17];
  const float* bih  = (const float*)d_in[18];
  const float* bhh  = (const float*)d_in[19];
  const float* rW12 = (const float*)d_in[20];
  const float* rb12 = (const float*)d_in[21];
  const float* rW3  = (const float*)d_in[22];
  const float* rb3  = (const float*)d_in[23];

  char* ws = (char*)d_ws;
  float* XgTab = (float*)(ws);
  float* XTab  = (float*)(ws + 2048);
  float* YTab  = (float*)(ws + 4096);
  float* ZTab  = (float*)(ws + 6144);
  float* Wf_cr = (float*)(ws + 8192);            // 9216 f
  float* b_cr  = (float*)(ws + 45056);           // 96 f
  float* Wf_dr = (float*)(ws + 45568);           // 9216 f
  float* b_dr  = (float*)(ws + 82432);           // 96 f
  u16*   pWB   = (u16*)(ws + 233472);            // 368640 B
  u16* h  = (u16*)(ws + 634880);
  u16* B1 = h  + (size_t)MROWS * 96;             // Y
  u16* B2 = B1 + (size_t)MROWS * 96;             // Z / Zd
  u16* ch = B2 + (size_t)MROWS * 96;             // fp16 c-state (18 MB)
  u16* Ssum = ch + (size_t)MROWS * 96;           // BN*96 bf16
  float* out = (float*)d_out;

  k_fold<<<2, 256, 0, stream>>>(crW, crB, drW, drB, gmW1,
                                Wf_cr, b_cr, Wf_dr, b_dr);
  k_tables2<<<1, 128, 0, stream>>>(eW1, eb1, eW2, eb2, gmW1, gmb1,
                                   crW, crB, drW, drB, Wf_cr, b_cr, Wf_dr, b_dr,
                                   XTab, XgTab, YTab, ZTab);
  k_prep2<<<20, 256, 0, stream>>>(crW, drW, gmW1, gmW2, rW12, Wih, Whh,
                                  Wf_cr, Wf_dr, pWB);
  k_init2<<<(MROWS * 12) / 256, 256, 0, stream>>>(inputs, XTab, YTab, ZTab, c0,
                                                  h, B1, B2, ch);

  for (int it = 0; it < 4; ++it){
    k_msg<<<1152 + 486, 256, 0, stream>>>(B2, B1, Ssum);
    k_glr10<<<GRID_TILE, 256, 0, stream>>>(B1, B2, Ssum, inputs, XgTab, pWB, gmb2,
                                           h, ch, bih, bhh, crB, drB, b_cr, b_dr,
                                           B1, B2, rb12, rW3, rb3,
                                           out + (size_t)it * MROWS, (it < 3) ? 1 : 0);
  }
}